// Round 18
// baseline (38.750 us; speedup 1.0000x reference)
//
#include <hip/hip_runtime.h>

// VIN forward — R18: R16 structure (best, 28.46us) + MLP de-broadcast.
// R17's 2-sample pipeline regressed (occupancy 71->38%) -> reverted.
// R16's fused MLP phase-2 had 32 broadcast ds_read_b128/thread (~5.1us/CU of
// LDS pipe — the R10 pathology reintroduced). Fix: 2 cols/thread, 4-way
// K-split, float2 weight loads -> 16 b128/thread, 64 float2 W2 loads, same
// FMA count. W2 L2 bytes unchanged (fundamental at 1 sample/block).

#define K_ITERS 10

__device__ __forceinline__ float shr1(float x) {   // lane i <- i-1, lane0 <- 0
    return __int_as_float(__builtin_amdgcn_mov_dpp(__float_as_int(x), 0x138, 0xF, 0xF, true));
}
__device__ __forceinline__ float shl1(float x) {   // lane i <- i+1, lane63 <- 0
    return __int_as_float(__builtin_amdgcn_mov_dpp(__float_as_int(x), 0x130, 0xF, 0xF, true));
}
__device__ __forceinline__ float max3(float a, float b, float c) {
    return fmaxf(fmaxf(a, b), c);   // -> v_max3_f32
}

__global__ __launch_bounds__(512) void vin_fused_kernel(
    const float* __restrict__ obs,     // [B,64,64,3]
    const float* __restrict__ W_phi,   // [3,3]
    const float* __restrict__ b_phi,   // [3]
    const float* __restrict__ W1,      // [36,256]
    const float* __restrict__ b1,      // [256]
    const float* __restrict__ W2,      // [256,256]
    const float* __restrict__ b2,      // [256]
    const float* __restrict__ Wl,      // [256,5]
    const float* __restrict__ bl,      // [5]
    float* __restrict__ out)           // [B,5]
{
    const int b   = blockIdx.x;
    const int tid = threadIdx.x;
    const int w   = tid >> 6;   // wave id 0..7: rows 8w .. 8w+7
    const int l   = tid & 63;   // lane = column

    __shared__ float v_s[64 * 64];     // 16 KB: final value map (gather only)
    __shared__ float bndU[2][9][64];   // v[7] of wave w-1 at [w]; [0]=0
    __shared__ float bndD[2][9][64];   // v[0] of wave w+1 at [w+1]; [8]=0
    __shared__ float rbU[9][64];       // rin row 8w-1 at [w]; [0]=0
    __shared__ float rbD[9][64];       // rin row 8w+8 at [w+1]; [8]=0
    __shared__ int   agent_pos;
    __shared__ float f_s[36];
    __shared__ __align__(8)  float part_s[4][256];   // 4 KB (phase1+2 partials)
    __shared__ __align__(16) float h1_s[256];        // 1 KB
    __shared__ float h2_s[256];                      // 1 KB
    __shared__ float red[8][5];

    const float* ob = obs + (size_t)b * (4096 * 3);

    const float w00 = W_phi[0], w01 = W_phi[1], w02 = W_phi[2];
    const float w10 = W_phi[3], w11 = W_phi[4], w12 = W_phi[5];
    const float w20 = W_phi[6], w21 = W_phi[7], w22 = W_phi[8];
    const float bp0 = b_phi[0], bp1 = b_phi[1], bp2 = b_phi[2];

    // ---- VI: load + phi for the 8 owned rows ----
    float pk[8], rik[8], rok[8];
    #pragma unroll
    for (int k = 0; k < 8; ++k) {
        const int cell = (8 * w + k) * 64 + l;
        const float o0 = ob[cell * 3 + 0];
        const float o1 = ob[cell * 3 + 1];
        const float o2 = ob[cell * 3 + 2];
        pk[k]  = fmaxf(fmaf(o2, w20, fmaf(o1, w10, fmaf(o0, w00, bp0))), 0.f);
        rik[k] = fmaxf(fmaf(o2, w21, fmaf(o1, w11, fmaf(o0, w01, bp1))), 0.f);
        rok[k] = fmaxf(fmaf(o2, w22, fmaf(o1, w12, fmaf(o0, w02, bp2))), 0.f);
        if (o1 > 0.5f) agent_pos = cell;   // one-hot agent: single writer
    }
    const float p0 = pk[0], p1 = pk[1], p2 = pk[2], p3 = pk[3];
    const float p4 = pk[4], p5 = pk[5], p6 = pk[6], p7 = pk[7];

    // Zero pad rows (written once) + static rin boundary rows.
    if (tid < 64) {
        bndU[0][0][l] = 0.f; bndU[1][0][l] = 0.f;
        bndD[0][8][l] = 0.f; bndD[1][8][l] = 0.f;
        rbU[0][l] = 0.f;     rbD[8][l] = 0.f;
    }
    rbU[w + 1][l] = rik[7];
    rbD[w][l]     = rik[0];
    __syncthreads();
    const float rinU_b = rbU[w][l];
    const float rinD_b = rbD[w + 1][l];

    // Folded per-direction constants aX = rin(neighbor X) - rout.
    // Out-of-grid terms = -rout <= 0 never win (v>=0 monotone, relu >= 0,
    // DPP zero-fill at wave edges, zero pad rows vertically).
    const float aU0 = rinU_b - rok[0], aU1 = rik[0] - rok[1], aU2 = rik[1] - rok[2], aU3 = rik[2] - rok[3];
    const float aU4 = rik[3] - rok[4], aU5 = rik[4] - rok[5], aU6 = rik[5] - rok[6], aU7 = rik[6] - rok[7];
    const float aD0 = rik[1] - rok[0], aD1 = rik[2] - rok[1], aD2 = rik[3] - rok[2], aD3 = rik[4] - rok[3];
    const float aD4 = rik[5] - rok[4], aD5 = rik[6] - rok[5], aD6 = rik[7] - rok[6], aD7 = rinD_b - rok[7];
    const float aL0 = shr1(rik[0]) - rok[0], aL1 = shr1(rik[1]) - rok[1], aL2 = shr1(rik[2]) - rok[2], aL3 = shr1(rik[3]) - rok[3];
    const float aL4 = shr1(rik[4]) - rok[4], aL5 = shr1(rik[5]) - rok[5], aL6 = shr1(rik[6]) - rok[6], aL7 = shr1(rik[7]) - rok[7];
    const float aR0 = shl1(rik[0]) - rok[0], aR1 = shl1(rik[1]) - rok[1], aR2 = shl1(rik[2]) - rok[2], aR3 = shl1(rik[3]) - rok[3];
    const float aR4 = shl1(rik[4]) - rok[4], aR5 = shl1(rik[5]) - rok[5], aR6 = shl1(rik[6]) - rok[6], aR7 = shl1(rik[7]) - rok[7];

    // Iter 0 peeled (v == 0): v = max(0, aU, aD, aL, aR).
    float v0 = fmaxf(max3(aU0, aD0, aL0), fmaxf(aR0, 0.f));
    float v1 = fmaxf(max3(aU1, aD1, aL1), fmaxf(aR1, 0.f));
    float v2 = fmaxf(max3(aU2, aD2, aL2), fmaxf(aR2, 0.f));
    float v3 = fmaxf(max3(aU3, aD3, aL3), fmaxf(aR3, 0.f));
    float v4 = fmaxf(max3(aU4, aD4, aL4), fmaxf(aR4, 0.f));
    float v5 = fmaxf(max3(aU5, aD5, aL5), fmaxf(aR5, 0.f));
    float v6 = fmaxf(max3(aU6, aD6, aL6), fmaxf(aR6, 0.f));
    float v7 = fmaxf(max3(aU7, aD7, aL7), fmaxf(aR7, 0.f));
    bndU[0][w + 1][l] = v7;
    bndD[0][w][l]     = v0;

    // Iters 1..9, fully unrolled; Jacobi via SSA names.
    #pragma unroll
    for (int it = 1; it < K_ITERS; ++it) {
        const int rd = (it - 1) & 1, wr = it & 1;
        __syncthreads();
        const float vU_b = bndU[rd][w][l];
        const float vD_b = bndD[rd][w + 1][l];

        float vL, vR, m;
        vL = shr1(v7); vR = shl1(v7);
        m = max3(fmaf(p7, v6, aU7), fmaf(p7, vD_b, aD7), fmaf(p7, vL, aL7));
        const float nv7 = max3(m, fmaf(p7, vR, aR7), v7);
        bndU[wr][w + 1][l] = nv7;

        vL = shr1(v0); vR = shl1(v0);
        m = max3(fmaf(p0, vU_b, aU0), fmaf(p0, v1, aD0), fmaf(p0, vL, aL0));
        const float nv0 = max3(m, fmaf(p0, vR, aR0), v0);
        bndD[wr][w][l] = nv0;

        vL = shr1(v1); vR = shl1(v1);
        m = max3(fmaf(p1, v0, aU1), fmaf(p1, v2, aD1), fmaf(p1, vL, aL1));
        const float nv1 = max3(m, fmaf(p1, vR, aR1), v1);

        vL = shr1(v2); vR = shl1(v2);
        m = max3(fmaf(p2, v1, aU2), fmaf(p2, v3, aD2), fmaf(p2, vL, aL2));
        const float nv2 = max3(m, fmaf(p2, vR, aR2), v2);

        vL = shr1(v3); vR = shl1(v3);
        m = max3(fmaf(p3, v2, aU3), fmaf(p3, v4, aD3), fmaf(p3, vL, aL3));
        const float nv3 = max3(m, fmaf(p3, vR, aR3), v3);

        vL = shr1(v4); vR = shl1(v4);
        m = max3(fmaf(p4, v3, aU4), fmaf(p4, v5, aD4), fmaf(p4, vL, aL4));
        const float nv4 = max3(m, fmaf(p4, vR, aR4), v4);

        vL = shr1(v5); vR = shl1(v5);
        m = max3(fmaf(p5, v4, aU5), fmaf(p5, v6, aD5), fmaf(p5, vL, aL5));
        const float nv5 = max3(m, fmaf(p5, vR, aR5), v5);

        vL = shr1(v6); vR = shl1(v6);
        m = max3(fmaf(p6, v5, aU6), fmaf(p6, v7, aD6), fmaf(p6, vL, aL6));
        const float nv6 = max3(m, fmaf(p6, vR, aR6), v6);

        v0 = nv0; v1 = nv1; v2 = nv2; v3 = nv3;
        v4 = nv4; v5 = nv5; v6 = nv6; v7 = nv7;
    }

    v_s[(8 * w + 0) * 64 + l] = v0;
    v_s[(8 * w + 1) * 64 + l] = v1;
    v_s[(8 * w + 2) * 64 + l] = v2;
    v_s[(8 * w + 3) * 64 + l] = v3;
    v_s[(8 * w + 4) * 64 + l] = v4;
    v_s[(8 * w + 5) * 64 + l] = v5;
    v_s[(8 * w + 6) * 64 + l] = v6;
    v_s[(8 * w + 7) * 64 + l] = v7;
    __syncthreads();

    // ---- Gather: 36 features into LDS ----
    if (tid < 36) {
        const int ap = agent_pos;
        const int ar = ap >> 6, ac = ap & 63;
        const int g  = tid / 9, o = tid % 9;
        const int rr = ar + o / 3 - 1;
        const int cc = ac + o % 3 - 1;
        float val = 0.f;
        if (rr >= 0 && rr < 64 && cc >= 0 && cc < 64) {
            const int cell = rr * 64 + cc;
            if      (g == 0) val = 1.f - ob[cell * 3 + 0];
            else if (g == 1) val = ob[cell * 3 + 1];
            else if (g == 2) val = ob[cell * 3 + 2];
            else             val = v_s[cell];
        }
        f_s[tid] = val;
    }
    __syncthreads();

    // ---- MLP phase 1: h1 = f @ W1 + b1 (4-way K-split, 2 cols/thread) ----
    {
        const int h  = tid >> 7;       // 0..3 -> rows [9h, 9h+9)
        const int cp = tid & 127;      // cols 2cp, 2cp+1
        float a0 = 0.f, a1 = 0.f;
        #pragma unroll
        for (int m = 0; m < 9; ++m) {
            const int i = 9 * h + m;
            const float2 wv = *reinterpret_cast<const float2*>(&W1[i * 256 + 2 * cp]);
            const float fv = f_s[i];
            a0 = fmaf(fv, wv.x, a0);
            a1 = fmaf(fv, wv.y, a1);
        }
        *reinterpret_cast<float2*>(&part_s[h][2 * cp]) = make_float2(a0, a1);
    }
    __syncthreads();
    if (tid < 256)
        h1_s[tid] = b1[tid] + ((part_s[0][tid] + part_s[1][tid]) +
                               (part_s[2][tid] + part_s[3][tid]));
    __syncthreads();

    // ---- MLP phase 2: h2 = h1 @ W2 + b2 (4-way K-split, 2 cols/thread):
    //      16 b128 h1-broadcasts/thread (was 32), 64 float2 W2 loads (was 128)
    {
        const int h  = tid >> 7;       // 0..3 -> rows [64h, 64h+64)
        const int cp = tid & 127;      // cols 2cp, 2cp+1
        float a0 = 0.f, a1 = 0.f;
        #pragma unroll
        for (int m4 = 0; m4 < 16; ++m4) {
            const int i = 64 * h + 4 * m4;
            const float4 hv = *reinterpret_cast<const float4*>(&h1_s[i]); // bcast
            const float2 wA = *reinterpret_cast<const float2*>(&W2[(i + 0) * 256 + 2 * cp]);
            const float2 wB = *reinterpret_cast<const float2*>(&W2[(i + 1) * 256 + 2 * cp]);
            const float2 wC = *reinterpret_cast<const float2*>(&W2[(i + 2) * 256 + 2 * cp]);
            const float2 wD = *reinterpret_cast<const float2*>(&W2[(i + 3) * 256 + 2 * cp]);
            a0 = fmaf(hv.x, wA.x, a0); a1 = fmaf(hv.x, wA.y, a1);
            a0 = fmaf(hv.y, wB.x, a0); a1 = fmaf(hv.y, wB.y, a1);
            a0 = fmaf(hv.z, wC.x, a0); a1 = fmaf(hv.z, wC.y, a1);
            a0 = fmaf(hv.w, wD.x, a0); a1 = fmaf(hv.w, wD.y, a1);
        }
        *reinterpret_cast<float2*>(&part_s[h][2 * cp]) = make_float2(a0, a1);
    }
    __syncthreads();
    if (tid < 256)
        h2_s[tid] = b2[tid] + ((part_s[0][tid] + part_s[1][tid]) +
                               (part_s[2][tid] + part_s[3][tid]));
    __syncthreads();

    // ---- MLP phase 3: logits (40 threads: 5 logits x 8 chunks of 32) ----
    if (tid < 40) {
        const int j  = tid % 5;
        const int ch = tid / 5;        // 0..7
        float acc = 0.f;
        #pragma unroll
        for (int m = 0; m < 32; ++m) {
            const int i = ch * 32 + m;
            acc = fmaf(h2_s[i], Wl[i * 5 + j], acc);
        }
        red[ch][j] = acc;
    }
    __syncthreads();
    if (tid < 5) {
        float o = bl[tid];
        #pragma unroll
        for (int ch = 0; ch < 8; ++ch) o += red[ch][tid];
        out[b * 5 + tid] = o;
    }
}

extern "C" void kernel_launch(void* const* d_in, const int* in_sizes, int n_in,
                              void* d_out, int out_size, void* d_ws, size_t ws_size,
                              hipStream_t stream) {
    const float* obs   = (const float*)d_in[0];
    const float* W_phi = (const float*)d_in[1];
    const float* b_phi = (const float*)d_in[2];
    const float* W1    = (const float*)d_in[3];
    const float* b1    = (const float*)d_in[4];
    const float* W2    = (const float*)d_in[5];
    const float* b2    = (const float*)d_in[6];
    const float* Wl    = (const float*)d_in[7];
    const float* bl    = (const float*)d_in[8];
    float* out = (float*)d_out;

    vin_fused_kernel<<<dim3(1024), dim3(512), 0, stream>>>(
        obs, W_phi, b_phi, W1, b1, W2, b2, Wl, bl, out);
}

// Round 19
// 27.487 us; speedup vs baseline: 1.4098x; 1.4098x over previous
//
#include <hip/hip_runtime.h>

// VIN forward — R19: fused, 2 samples/block on CONCURRENT waves.
// R18 (float2+2col MLP) regressed like R11/R17 -> reverted to R16's MLP shape.
// New mechanism: block=1024thr, waves 0-7 = sample b, waves 8-15 = sample
// b+512, running VI concurrently (R17 serialized them -> lost TLP; here wave
// parallelism is preserved: 2 blocks/CU x 16 waves = 32 waves/CU, same as
// R16). Joint MLP: one W2 dword feeds both samples' FMAs -> W2 L2 requests
// and bytes halve (256->128MB). VI codegen per sample identical to R16.

#define K_ITERS 10

__device__ __forceinline__ float shr1(float x) {   // lane i <- i-1, lane0 <- 0
    return __int_as_float(__builtin_amdgcn_mov_dpp(__float_as_int(x), 0x138, 0xF, 0xF, true));
}
__device__ __forceinline__ float shl1(float x) {   // lane i <- i+1, lane63 <- 0
    return __int_as_float(__builtin_amdgcn_mov_dpp(__float_as_int(x), 0x130, 0xF, 0xF, true));
}
__device__ __forceinline__ float max3(float a, float b, float c) {
    return fmaxf(fmaxf(a, b), c);   // -> v_max3_f32
}

// One sample's VI (8 waves of the calling half). Barriers inside are
// block-wide; both samples call with aligned control flow.
__device__ __forceinline__ void vi_sample(
    const float* __restrict__ pk, const float* __restrict__ rik,
    const float* __restrict__ rok, int w, int l,
    float (&bndU)[2][9][64], float (&bndD)[2][9][64],
    float (&rbU)[9][64], float (&rbD)[9][64],
    float* __restrict__ v_s)
{
    rbU[w + 1][l] = rik[7];
    rbD[w][l]     = rik[0];
    __syncthreads();
    const float rinU_b = rbU[w][l];
    const float rinD_b = rbD[w + 1][l];

    const float p0 = pk[0], p1 = pk[1], p2 = pk[2], p3 = pk[3];
    const float p4 = pk[4], p5 = pk[5], p6 = pk[6], p7 = pk[7];

    // aX = rin(neighbor X) - rout; out-of-grid terms = -rout <= 0 never win
    // (v>=0 monotone, relu>=0, DPP zero-fill, zero pad rows).
    const float aU0 = rinU_b - rok[0], aU1 = rik[0] - rok[1], aU2 = rik[1] - rok[2], aU3 = rik[2] - rok[3];
    const float aU4 = rik[3] - rok[4], aU5 = rik[4] - rok[5], aU6 = rik[5] - rok[6], aU7 = rik[6] - rok[7];
    const float aD0 = rik[1] - rok[0], aD1 = rik[2] - rok[1], aD2 = rik[3] - rok[2], aD3 = rik[4] - rok[3];
    const float aD4 = rik[5] - rok[4], aD5 = rik[6] - rok[5], aD6 = rik[7] - rok[6], aD7 = rinD_b - rok[7];
    const float aL0 = shr1(rik[0]) - rok[0], aL1 = shr1(rik[1]) - rok[1], aL2 = shr1(rik[2]) - rok[2], aL3 = shr1(rik[3]) - rok[3];
    const float aL4 = shr1(rik[4]) - rok[4], aL5 = shr1(rik[5]) - rok[5], aL6 = shr1(rik[6]) - rok[6], aL7 = shr1(rik[7]) - rok[7];
    const float aR0 = shl1(rik[0]) - rok[0], aR1 = shl1(rik[1]) - rok[1], aR2 = shl1(rik[2]) - rok[2], aR3 = shl1(rik[3]) - rok[3];
    const float aR4 = shl1(rik[4]) - rok[4], aR5 = shl1(rik[5]) - rok[5], aR6 = shl1(rik[6]) - rok[6], aR7 = shl1(rik[7]) - rok[7];

    // Iter 0 peeled (v == 0).
    float v0 = fmaxf(max3(aU0, aD0, aL0), fmaxf(aR0, 0.f));
    float v1 = fmaxf(max3(aU1, aD1, aL1), fmaxf(aR1, 0.f));
    float v2 = fmaxf(max3(aU2, aD2, aL2), fmaxf(aR2, 0.f));
    float v3 = fmaxf(max3(aU3, aD3, aL3), fmaxf(aR3, 0.f));
    float v4 = fmaxf(max3(aU4, aD4, aL4), fmaxf(aR4, 0.f));
    float v5 = fmaxf(max3(aU5, aD5, aL5), fmaxf(aR5, 0.f));
    float v6 = fmaxf(max3(aU6, aD6, aL6), fmaxf(aR6, 0.f));
    float v7 = fmaxf(max3(aU7, aD7, aL7), fmaxf(aR7, 0.f));
    bndU[0][w + 1][l] = v7;
    bndD[0][w][l]     = v0;

    #pragma unroll
    for (int it = 1; it < K_ITERS; ++it) {
        const int rd = (it - 1) & 1, wr = it & 1;
        __syncthreads();
        const float vU_b = bndU[rd][w][l];
        const float vD_b = bndD[rd][w + 1][l];

        float vL, vR, m;
        vL = shr1(v7); vR = shl1(v7);
        m = max3(fmaf(p7, v6, aU7), fmaf(p7, vD_b, aD7), fmaf(p7, vL, aL7));
        const float nv7 = max3(m, fmaf(p7, vR, aR7), v7);
        bndU[wr][w + 1][l] = nv7;

        vL = shr1(v0); vR = shl1(v0);
        m = max3(fmaf(p0, vU_b, aU0), fmaf(p0, v1, aD0), fmaf(p0, vL, aL0));
        const float nv0 = max3(m, fmaf(p0, vR, aR0), v0);
        bndD[wr][w][l] = nv0;

        vL = shr1(v1); vR = shl1(v1);
        m = max3(fmaf(p1, v0, aU1), fmaf(p1, v2, aD1), fmaf(p1, vL, aL1));
        const float nv1 = max3(m, fmaf(p1, vR, aR1), v1);

        vL = shr1(v2); vR = shl1(v2);
        m = max3(fmaf(p2, v1, aU2), fmaf(p2, v3, aD2), fmaf(p2, vL, aL2));
        const float nv2 = max3(m, fmaf(p2, vR, aR2), v2);

        vL = shr1(v3); vR = shl1(v3);
        m = max3(fmaf(p3, v2, aU3), fmaf(p3, v4, aD3), fmaf(p3, vL, aL3));
        const float nv3 = max3(m, fmaf(p3, vR, aR3), v3);

        vL = shr1(v4); vR = shl1(v4);
        m = max3(fmaf(p4, v3, aU4), fmaf(p4, v5, aD4), fmaf(p4, vL, aL4));
        const float nv4 = max3(m, fmaf(p4, vR, aR4), v4);

        vL = shr1(v5); vR = shl1(v5);
        m = max3(fmaf(p5, v4, aU5), fmaf(p5, v6, aD5), fmaf(p5, vL, aL5));
        const float nv5 = max3(m, fmaf(p5, vR, aR5), v5);

        vL = shr1(v6); vR = shl1(v6);
        m = max3(fmaf(p6, v5, aU6), fmaf(p6, v7, aD6), fmaf(p6, vL, aL6));
        const float nv6 = max3(m, fmaf(p6, vR, aR6), v6);

        v0 = nv0; v1 = nv1; v2 = nv2; v3 = nv3;
        v4 = nv4; v5 = nv5; v6 = nv6; v7 = nv7;
    }

    v_s[(8 * w + 0) * 64 + l] = v0;
    v_s[(8 * w + 1) * 64 + l] = v1;
    v_s[(8 * w + 2) * 64 + l] = v2;
    v_s[(8 * w + 3) * 64 + l] = v3;
    v_s[(8 * w + 4) * 64 + l] = v4;
    v_s[(8 * w + 5) * 64 + l] = v5;
    v_s[(8 * w + 6) * 64 + l] = v6;
    v_s[(8 * w + 7) * 64 + l] = v7;
}

__global__ __launch_bounds__(1024) void vin_fused2c_kernel(
    const float* __restrict__ obs,     // [B,64,64,3]
    const float* __restrict__ W_phi,   // [3,3]
    const float* __restrict__ b_phi,   // [3]
    const float* __restrict__ W1,      // [36,256]
    const float* __restrict__ b1,      // [256]
    const float* __restrict__ W2,      // [256,256]
    const float* __restrict__ b2,      // [256]
    const float* __restrict__ Wl,      // [256,5]
    const float* __restrict__ bl,      // [5]
    float* __restrict__ out)           // [B,5]
{
    const int tid = threadIdx.x;
    const int s   = tid >> 9;          // sample half 0/1
    const int st  = tid & 511;         // thread id within half
    const int w   = st >> 6;           // per-sample wave 0..7
    const int l   = st & 63;           // lane = column
    const int b   = blockIdx.x + s * 512;

    __shared__ float v_s[2][4096];                    // 32 KB
    __shared__ float bndU[2][2][9][64];               // 9 KB [s][buf][row][col]
    __shared__ float bndD[2][2][9][64];               // 9 KB
    __shared__ float rbU[2][9][64], rbD[2][9][64];    // 9 KB
    __shared__ int   agent_pos[2];
    __shared__ __align__(8)  float f_s[36][2];        // [feature][sample]
    __shared__ float part_s[4][2][256];               // 8 KB
    __shared__ __align__(16) float h1_s[256][2];      // 2 KB [row][sample]
    __shared__ float h2_s[2][256];                    // 2 KB
    __shared__ float red[8][2][5];

    const float* ob = obs + (size_t)b * 12288;

    const float w00 = W_phi[0], w01 = W_phi[1], w02 = W_phi[2];
    const float w10 = W_phi[3], w11 = W_phi[4], w12 = W_phi[5];
    const float w20 = W_phi[6], w21 = W_phi[7], w22 = W_phi[8];
    const float bp0 = b_phi[0], bp1 = b_phi[1], bp2 = b_phi[2];

    // ---- load + phi for this sample's 8 owned rows ----
    float pk[8], rik[8], rok[8];
    #pragma unroll
    for (int k = 0; k < 8; ++k) {
        const int cell = (8 * w + k) * 64 + l;
        const float o0 = ob[cell * 3 + 0];
        const float o1 = ob[cell * 3 + 1];
        const float o2 = ob[cell * 3 + 2];
        pk[k]  = fmaxf(fmaf(o2, w20, fmaf(o1, w10, fmaf(o0, w00, bp0))), 0.f);
        rik[k] = fmaxf(fmaf(o2, w21, fmaf(o1, w11, fmaf(o0, w01, bp1))), 0.f);
        rok[k] = fmaxf(fmaf(o2, w22, fmaf(o1, w12, fmaf(o0, w02, bp2))), 0.f);
        if (o1 > 0.5f) agent_pos[s] = cell;   // one-hot: single writer per sample
    }

    // Zero pad rows (each half zeros its own sample's pads).
    if (st < 64) {
        bndU[s][0][0][l] = 0.f; bndU[s][1][0][l] = 0.f;
        bndD[s][0][8][l] = 0.f; bndD[s][1][8][l] = 0.f;
        rbU[s][0][l] = 0.f;     rbD[s][8][l] = 0.f;
    }

    // ---- VI (both samples concurrently; barriers aligned) ----
    vi_sample(pk, rik, rok, w, l, bndU[s], bndD[s], rbU[s], rbD[s], v_s[s]);
    __syncthreads();

    // ---- gather 36 features per sample ----
    if (st < 36) {
        const int ap = agent_pos[s];
        const int ar = ap >> 6, ac = ap & 63;
        const int g  = st / 9, o = st % 9;
        const int rr = ar + o / 3 - 1;
        const int cc = ac + o % 3 - 1;
        float val = 0.f;
        if (rr >= 0 && rr < 64 && cc >= 0 && cc < 64) {
            const int cell = rr * 64 + cc;
            if      (g == 0) val = 1.f - ob[cell * 3 + 0];
            else if (g == 1) val = ob[cell * 3 + 1];
            else if (g == 2) val = ob[cell * 3 + 2];
            else             val = v_s[s][cell];
        }
        f_s[st][s] = val;
    }
    __syncthreads();

    // ---- MLP phase 1: 36->256 joint (4-way K-split; one W1 dword -> 2 FMA) ----
    {
        const int q = tid >> 8;        // 0..3 -> rows [9q, 9q+9)
        const int c = tid & 255;
        float a0 = 0.f, a1 = 0.f;
        #pragma unroll
        for (int m = 0; m < 9; ++m) {
            const int i = 9 * q + m;
            const float wv = W1[i * 256 + c];
            const float2 fv = *reinterpret_cast<const float2*>(&f_s[i][0]); // bcast
            a0 = fmaf(fv.x, wv, a0);
            a1 = fmaf(fv.y, wv, a1);
        }
        part_s[q][0][c] = a0;
        part_s[q][1][c] = a1;
    }
    __syncthreads();
    if (tid < 512) {
        const int ss = tid >> 8, c = tid & 255;
        h1_s[c][ss] = b1[c] + ((part_s[0][ss][c] + part_s[1][ss][c]) +
                               (part_s[2][ss][c] + part_s[3][ss][c]));
    }
    __syncthreads();

    // ---- MLP phase 2: 256->256 joint (4-way K-split; one W2 dword -> 2 FMA;
    //      one b128 h1 read covers 2 rows x 2 samples) ----
    {
        const int q = tid >> 8;        // 0..3 -> rows [64q, 64q+64)
        const int c = tid & 255;
        float a0 = 0.f, a1 = 0.f;
        #pragma unroll
        for (int m2 = 0; m2 < 32; ++m2) {
            const int i = 64 * q + 2 * m2;
            const float4 hv = *reinterpret_cast<const float4*>(&h1_s[i][0]); // bcast
            const float wv0 = W2[(i + 0) * 256 + c];
            const float wv1 = W2[(i + 1) * 256 + c];
            a0 = fmaf(hv.x, wv0, a0);  // h1[i][A]
            a1 = fmaf(hv.y, wv0, a1);  // h1[i][B]
            a0 = fmaf(hv.z, wv1, a0);  // h1[i+1][A]
            a1 = fmaf(hv.w, wv1, a1);  // h1[i+1][B]
        }
        part_s[q][0][c] = a0;
        part_s[q][1][c] = a1;
    }
    __syncthreads();
    if (tid < 512) {
        const int ss = tid >> 8, c = tid & 255;
        h2_s[ss][c] = b2[c] + ((part_s[0][ss][c] + part_s[1][ss][c]) +
                               (part_s[2][ss][c] + part_s[3][ss][c]));
    }
    __syncthreads();

    // ---- logits: 80 threads = 2 samples x 5 logits x 8 chunks of 32 ----
    if (tid < 80) {
        const int ss = tid & 1;
        const int j  = (tid >> 1) % 5;
        const int ch = tid / 10;       // 0..7
        float acc = 0.f;
        #pragma unroll
        for (int m = 0; m < 32; ++m) {
            const int i = ch * 32 + m;
            acc = fmaf(h2_s[ss][i], Wl[i * 5 + j], acc);
        }
        red[ch][ss][j] = acc;
    }
    __syncthreads();
    if (tid < 10) {
        const int ss = tid & 1, j = tid >> 1;
        float o = bl[j];
        #pragma unroll
        for (int ch = 0; ch < 8; ++ch) o += red[ch][ss][j];
        out[(blockIdx.x + ss * 512) * 5 + j] = o;
    }
}

extern "C" void kernel_launch(void* const* d_in, const int* in_sizes, int n_in,
                              void* d_out, int out_size, void* d_ws, size_t ws_size,
                              hipStream_t stream) {
    const float* obs   = (const float*)d_in[0];
    const float* W_phi = (const float*)d_in[1];
    const float* b_phi = (const float*)d_in[2];
    const float* W1    = (const float*)d_in[3];
    const float* b1    = (const float*)d_in[4];
    const float* W2    = (const float*)d_in[5];
    const float* b2    = (const float*)d_in[6];
    const float* Wl    = (const float*)d_in[7];
    const float* bl    = (const float*)d_in[8];
    float* out = (float*)d_out;

    vin_fused2c_kernel<<<dim3(512), dim3(1024), 0, stream>>>(
        obs, W_phi, b_phi, W1, b1, W2, b2, Wl, bl, out);
}